// Round 5
// baseline (971.371 us; speedup 1.0000x reference)
//
#include <hip/hip_runtime.h>

#define T_STEPS 512
#define BATCH   2048
#define ISZ     128
#define HSZ     64
#define VSZ     128
#define ZSZ     192   // I + H

#define MBLK    8     // batch rows per recurrence block -> 256 blocks
#define ATHREADS 256  // 4 waves, all P
#define HLD     72    // hbuf row stride in bf16 (144 B, 16B-aligned)

typedef __attribute__((ext_vector_type(8))) short bf16x8;
typedef __attribute__((ext_vector_type(4))) float f32x4;

__device__ __forceinline__ unsigned short f2bf(float x) {
  union { float f; unsigned int u; } v; v.f = x;
  unsigned int u = v.u;
  unsigned int r = (u + 0x7fffu + ((u >> 16) & 1u)) >> 16;  // RNE
  return (unsigned short)r;
}

__device__ __forceinline__ float fsigmoid(float x) {
  return 1.0f / (1.0f + __expf(-x));
}

__device__ __forceinline__ float ftanh(float x) {
  x = fminf(fmaxf(x, -15.0f), 15.0f);
  float e = __expf(-2.0f * x);
  return (1.0f - e) / (1.0f + e);
}

// ================= Kernel A: recurrence only =================
__global__ __launch_bounds__(ATHREADS) void lstm_rec(
    const float* __restrict__ x,
    const float* __restrict__ h0,
    const float* __restrict__ c0,
    const float* __restrict__ Wf,  const float* __restrict__ bf_,
    const float* __restrict__ Wif, const float* __restrict__ bif_,
    const float* __restrict__ Wic, const float* __restrict__ bic_,
    const float* __restrict__ Wo,  const float* __restrict__ bo_,
    float* __restrict__ out)
{
  __shared__ unsigned short hbuf[2][16][HLD];

  const int tid  = threadIdx.x;
  const int wv   = tid >> 6;     // 0..3, owns h-cols [16wv, 16wv+16)
  const int ln   = tid & 63;
  const int lrow = ln & 15;
  const int lkg  = ln >> 4;
  const int b0   = blockIdx.x * MBLK;
  const int hcol = 16 * wv + lrow;

  const float* Wg_[4] = {Wf, Wif, Wic, Wo};
  const float* bg_[4] = {bf_, bif_, bic_, bo_};

  // weight fragments: x-part (K=128) and h-part (K=64), B-operands
  bf16x8 fragWx[4][4];
  bf16x8 fragWh[4][2];
#pragma unroll
  for (int g = 0; g < 4; ++g) {
#pragma unroll
    for (int kf = 0; kf < 4; ++kf) {
      const float* p = Wg_[g] + hcol * ZSZ + kf * 32 + 8 * lkg;
      bf16x8 f;
#pragma unroll
      for (int e = 0; e < 8; ++e) f[e] = (short)f2bf(p[e]);
      fragWx[g][kf] = f;
    }
#pragma unroll
    for (int kf = 0; kf < 2; ++kf) {
      const float* p = Wg_[g] + hcol * ZSZ + ISZ + kf * 32 + 8 * lkg;
      bf16x8 f;
#pragma unroll
      for (int e = 0; e < 8; ++e) f[e] = (short)f2bf(p[e]);
      fragWh[g][kf] = f;
    }
  }
  float biasG[4];
#pragma unroll
  for (int g = 0; g < 4; ++g) biasG[g] = bg_[g][hcol];

  // cell state, redistributed layout: lane (lkg,lrow) owns rows 2lkg,2lkg+1 at hcol
  float cst[2];
#pragma unroll
  for (int j = 0; j < 2; ++j)
    cst[j] = c0[(b0 + 2 * lkg + j) * HSZ + hcol];

  // zero hbuf (rows 8..15 stay zero), stage h0 rows 0..7
  for (int i = tid; i < 2 * 16 * HLD; i += ATHREADS)
    ((unsigned short*)hbuf)[i] = 0;
  __syncthreads();
  {
    int idx = tid * 2, r = idx >> 6, c = idx & 63;
    hbuf[0][r][c]     = f2bf(h0[(b0 + r) * HSZ + c]);
    hbuf[0][r][c + 1] = f2bf(h0[(b0 + r) * HSZ + c + 1]);
  }
  __syncthreads();

  // x pipeline: xfrag = x[t] (ready), xraw = x[t+1] (in flight)
  const int rowx = min(b0 + lrow, BATCH - 1);  // rows 8..15 are junk A-rows
  const int xoff = 8 * lkg;
  f32x4 xraw[4][2];
  bf16x8 xfrag[4];
  {
    const float* xt = x + (size_t)rowx * ISZ;
#pragma unroll
    for (int kf = 0; kf < 4; ++kf) {
      f32x4 a = *(const f32x4*)&xt[kf * 32 + xoff];
      f32x4 b = *(const f32x4*)&xt[kf * 32 + xoff + 4];
      bf16x8 f;
#pragma unroll
      for (int j = 0; j < 4; ++j) { f[j] = (short)f2bf(a[j]); f[4 + j] = (short)f2bf(b[j]); }
      xfrag[kf] = f;
    }
    const float* xn = x + (size_t)BATCH * ISZ + (size_t)rowx * ISZ;
#pragma unroll
    for (int kf = 0; kf < 4; ++kf) {
      xraw[kf][0] = *(const f32x4*)&xn[kf * 32 + xoff];
      xraw[kf][1] = *(const f32x4*)&xn[kf * 32 + xoff + 4];
    }
  }

  const size_t probs_elems = (size_t)T_STEPS * BATCH * VSZ;
  unsigned short* hout = (unsigned short*)out;  // h[t+1] stash: first 128B of each 512B probs row

  for (int t = 0; t < T_STEPS; ++t) {
    // x-part MFMAs (independent of h) before the barrier
    f32x4 acc[4];
#pragma unroll
    for (int g = 0; g < 4; ++g) acc[g] = (f32x4){biasG[g], biasG[g], biasG[g], biasG[g]};
#pragma unroll
    for (int kf = 0; kf < 4; ++kf)
#pragma unroll
      for (int g = 0; g < 4; ++g)
        acc[g] = __builtin_amdgcn_mfma_f32_16x16x32_bf16(xfrag[kf], fragWx[g][kf], acc[g], 0, 0, 0);
    __builtin_amdgcn_sched_barrier(0);

    // barrier: order prev step's hbuf writes vs this step's reads (LDS only, no vmcnt drain)
    asm volatile("s_waitcnt lgkmcnt(0)\n\ts_barrier" ::: "memory");
    __builtin_amdgcn_sched_barrier(0);

    // h-part MFMAs
    const unsigned short* hrow = &hbuf[t & 1][lrow][0];
    const bf16x8 hf0 = *(const bf16x8*)&hrow[xoff];
    const bf16x8 hf1 = *(const bf16x8*)&hrow[32 + xoff];
#pragma unroll
    for (int g = 0; g < 4; ++g)
      acc[g] = __builtin_amdgcn_mfma_f32_16x16x32_bf16(hf0, fragWh[g][0], acc[g], 0, 0, 0);
#pragma unroll
    for (int g = 0; g < 4; ++g)
      acc[g] = __builtin_amdgcn_mfma_f32_16x16x32_bf16(hf1, fragWh[g][1], acc[g], 0, 0, 0);

    // redistribute: lane (lkg,lrow) takes rows 2lkg,2lkg+1 from lanes holding rows 0..7
    const int src = (lkg >> 1) * 16 + lrow;
    const bool odd = (lkg & 1);
    float gv[4][2];
#pragma unroll
    for (int g = 0; g < 4; ++g) {
      float p0 = __shfl(acc[g][0], src);
      float p2 = __shfl(acc[g][2], src);
      float p1 = __shfl(acc[g][1], src);
      float p3 = __shfl(acc[g][3], src);
      gv[g][0] = odd ? p2 : p0;
      gv[g][1] = odd ? p3 : p1;
    }

    // cell update: 2 valid cells per lane
    float hh[2];
#pragma unroll
    for (int j = 0; j < 2; ++j) {
      float fg = fsigmoid(gv[0][j]);
      float ig = fsigmoid(gv[1][j]);
      float cd = ftanh(gv[2][j]);
      float og = fsigmoid(gv[3][j]);
      float c  = cst[j] * fg + cd * ig;
      cst[j] = c;
      hh[j] = ftanh(c) * og;
    }

    // publish h[t+1] to LDS ring + global stash for kernel B
    const int ns = (t + 1) & 1;
#pragma unroll
    for (int j = 0; j < 2; ++j) {
      const int r = 2 * lkg + j;
      const unsigned short hb = f2bf(hh[j]);
      hbuf[ns][r][hcol] = hb;
      hout[((size_t)t * BATCH + b0 + r) * (2 * VSZ) + hcol] = hb;
    }

    // convert x[t+1] (loads issued a full step ago), issue x[t+2]
    if (t + 1 < T_STEPS) {
#pragma unroll
      for (int kf = 0; kf < 4; ++kf) {
        bf16x8 f;
#pragma unroll
        for (int j = 0; j < 4; ++j) {
          f[j]     = (short)f2bf(xraw[kf][0][j]);
          f[4 + j] = (short)f2bf(xraw[kf][1][j]);
        }
        xfrag[kf] = f;
      }
    }
    if (t + 2 < T_STEPS) {
      const float* xn = x + (size_t)(t + 2) * BATCH * ISZ + (size_t)rowx * ISZ;
#pragma unroll
      for (int kf = 0; kf < 4; ++kf) {
        xraw[kf][0] = *(const f32x4*)&xn[kf * 32 + xoff];
        xraw[kf][1] = *(const f32x4*)&xn[kf * 32 + xoff + 4];
      }
    }

    if (t == T_STEPS - 1) {
#pragma unroll
      for (int j = 0; j < 2; ++j) {
        const int r = 2 * lkg + j;
        out[probs_elems + (size_t)(b0 + r) * HSZ + hcol] = hh[j];
        out[probs_elems + (size_t)BATCH * HSZ + (size_t)(b0 + r) * HSZ + hcol] = cst[j];
      }
    }
  }
}

// ========== Kernel B: out-proj + softmax, fully parallel over T x B ==========
#define BBLOCKS 2048
__global__ __launch_bounds__(256) void lstm_out(
    const float* __restrict__ Wout, const float* __restrict__ bout_,
    float* __restrict__ out)
{
  const int tid  = threadIdx.x;
  const int wv   = tid >> 6;
  const int ln   = tid & 63;
  const int lrow = ln & 15;
  const int lkg  = ln >> 4;

  bf16x8 fragWo[8][2];
#pragma unroll
  for (int rf = 0; rf < 8; ++rf)
#pragma unroll
    for (int kf = 0; kf < 2; ++kf) {
      const float* p = Wout + (16 * rf + lrow) * HSZ + kf * 32 + 8 * lkg;
      bf16x8 f;
#pragma unroll
      for (int e = 0; e < 8; ++e) f[e] = (short)f2bf(p[e]);
      fragWo[rf][kf] = f;
    }
  f32x4 boV[8];
#pragma unroll
  for (int rf = 0; rf < 8; ++rf) boV[rf] = *(const f32x4*)&bout_[16 * rf + 4 * lkg];

  const unsigned short* hin = (const unsigned short*)out;
  const int NT = T_STEPS * (BATCH / 16);   // 65536 tiles
  const int nw = BBLOCKS * 4;

  for (int tile = blockIdx.x * 4 + wv; tile < NT; tile += nw) {
    const int t  = tile >> 7;
    const int b0 = (tile & 127) * 16;

    // h[t+1] bf16 stashed at head of this row's probs slot (written by kernel A)
    const unsigned short* hr = hin + ((size_t)t * BATCH + b0 + lrow) * (2 * VSZ);
    const bf16x8 hb0 = *(const bf16x8*)&hr[8 * lkg];
    const bf16x8 hb1 = *(const bf16x8*)&hr[32 + 8 * lkg];

    // transposed out-proj: C[logit][batch], batch = lane&15
    f32x4 lac[8];
#pragma unroll
    for (int rf = 0; rf < 8; ++rf) {
      lac[rf] = boV[rf];
      lac[rf] = __builtin_amdgcn_mfma_f32_16x16x32_bf16(fragWo[rf][0], hb0, lac[rf], 0, 0, 0);
      lac[rf] = __builtin_amdgcn_mfma_f32_16x16x32_bf16(fragWo[rf][1], hb1, lac[rf], 0, 0, 0);
    }

    // softmax: lane holds 32 of 128 logits for batch row b0+lrow
    float m = -1e30f;
#pragma unroll
    for (int rf = 0; rf < 8; ++rf)
#pragma unroll
      for (int e = 0; e < 4; ++e) m = fmaxf(m, lac[rf][e]);
    m = fmaxf(m, __shfl_xor(m, 16));
    m = fmaxf(m, __shfl_xor(m, 32));
    float s = 0.0f;
#pragma unroll
    for (int rf = 0; rf < 8; ++rf)
#pragma unroll
      for (int e = 0; e < 4; ++e) {
        float p = __expf(lac[rf][e] - m);
        lac[rf][e] = p;
        s += p;
      }
    s += __shfl_xor(s, 16);
    s += __shfl_xor(s, 32);
    const float inv = 1.0f / s;

    float* orow = &out[((size_t)t * BATCH + b0 + lrow) * VSZ];
#pragma unroll
    for (int rf = 0; rf < 8; ++rf) {
      f32x4 pv = lac[rf] * inv;
      *(f32x4*)&orow[16 * rf + 4 * lkg] = pv;   // overwrites the h stash bytes too
    }
  }
}

extern "C" void kernel_launch(void* const* d_in, const int* in_sizes, int n_in,
                              void* d_out, int out_size, void* d_ws, size_t ws_size,
                              hipStream_t stream) {
  const float* x    = (const float*)d_in[0];
  const float* h0   = (const float*)d_in[1];
  const float* c0   = (const float*)d_in[2];
  const float* Wf   = (const float*)d_in[3];
  const float* bf_  = (const float*)d_in[4];
  const float* Wif  = (const float*)d_in[5];
  const float* bif_ = (const float*)d_in[6];
  const float* Wic  = (const float*)d_in[7];
  const float* bic_ = (const float*)d_in[8];
  const float* Wo   = (const float*)d_in[9];
  const float* bo_  = (const float*)d_in[10];
  const float* Wout = (const float*)d_in[11];
  const float* bout = (const float*)d_in[12];
  float* out = (float*)d_out;

  hipLaunchKernelGGL(lstm_rec, dim3(BATCH / MBLK), dim3(ATHREADS), 0, stream,
                     x, h0, c0, Wf, bf_, Wif, bif_, Wic, bic_, Wo, bo_, out);
  hipLaunchKernelGGL(lstm_out, dim3(BBLOCKS), dim3(256), 0, stream,
                     Wout, bout, out);
}

// Round 6
// 906.199 us; speedup vs baseline: 1.0719x; 1.0719x over previous
//
#include <hip/hip_runtime.h>
#include <hip/hip_bf16.h>

#define T_STEPS 512
#define BATCH   2048
#define ISZ     128
#define HSZ     64
#define VSZ     128
#define ZSZ     192   // I + H

#define MBLK    8     // batch rows per recurrence block -> 256 blocks
#define ATHREADS 512  // 4 P-waves + 4 X-waves
#define HLD     72    // hbuf row stride (bf16)
#define GRD     18    // gbuf row-dim stride (16 rows + 2 pad) in floats
#define GSLOT   (4 * 64 * GRD)   // floats per ring slot (4 gates x 64 cols x GRD)

typedef __attribute__((ext_vector_type(8))) short bf16x8;
typedef __attribute__((ext_vector_type(4))) float f32x4;

#define WG_SCOPE __HIP_MEMORY_SCOPE_WORKGROUP

__device__ __forceinline__ unsigned short f2bf(float x) {
  union { float f; unsigned int u; } v; v.f = x;
  unsigned int u = v.u;
  unsigned int r = (u + 0x7fffu + ((u >> 16) & 1u)) >> 16;  // RNE
  return (unsigned short)r;
}

__device__ __forceinline__ unsigned short f2bf_hw(float x) {
  __hip_bfloat16 b = __float2bfloat16(x);   // RNE, native cvt (pk-fusable)
  return *reinterpret_cast<unsigned short*>(&b);
}

__device__ __forceinline__ float fsigmoid(float x) {
  return 1.0f / (1.0f + __expf(-x));
}

__device__ __forceinline__ float ftanh(float x) {
  x = fminf(fmaxf(x, -15.0f), 15.0f);
  float e = __expf(-2.0f * x);
  return (1.0f - e) / (1.0f + e);
}

// ================= Kernel A: recurrence (P-waves) + x-GEMM producers (X-waves) ==
__global__ __launch_bounds__(ATHREADS, 2) void lstm_rec(
    const float* __restrict__ x,
    const float* __restrict__ h0,
    const float* __restrict__ c0,
    const float* __restrict__ Wf,  const float* __restrict__ bf_,
    const float* __restrict__ Wif, const float* __restrict__ bif_,
    const float* __restrict__ Wic, const float* __restrict__ bic_,
    const float* __restrict__ Wo,  const float* __restrict__ bo_,
    float* __restrict__ out)
{
  __shared__ float gbuf[3][GSLOT];            // x-part pre-activations ring
  __shared__ unsigned short hbuf[2][16][HLD]; // h state ring (bf16)
  __shared__ int xprod;   // X-wave completions (4 per step)
  __shared__ int pcons;   // P-wave g consumptions (4 per step)
  __shared__ int pbar;    // P-wave step completions (4 per step)

  const int tid  = threadIdx.x;
  const int wv   = tid >> 6;     // 0..3 = P, 4..7 = X
  const int ln   = tid & 63;
  const int lrow = ln & 15;
  const int lkg  = ln >> 4;
  const int b0   = blockIdx.x * MBLK;

  if (tid == 0) { xprod = 0; pcons = 0; pbar = 0; }
  for (int i = tid; i < 2 * 16 * HLD; i += ATHREADS)
    ((unsigned short*)hbuf)[i] = 0;
  __syncthreads();
  if (tid < 256) {   // stage h0 rows 0..7
    int idx = tid * 2, r = idx >> 6, c = idx & 63;
    hbuf[0][r][c]     = f2bf(h0[(b0 + r) * HSZ + c]);
    hbuf[0][r][c + 1] = f2bf(h0[(b0 + r) * HSZ + c + 1]);
  }
  __syncthreads();

  const float* Wg_[4] = {Wf, Wif, Wic, Wo};
  const float* bg_[4] = {bf_, bif_, bic_, bo_};
  const size_t probs_elems = (size_t)T_STEPS * BATCH * VSZ;

  if (wv < 4) {
    // ================= P-wave: minimal serial chain =================
    const int hcol = 16 * wv + lrow;

    bf16x8 fragWh[4][2];
#pragma unroll
    for (int g = 0; g < 4; ++g)
#pragma unroll
      for (int kf = 0; kf < 2; ++kf) {
        const float* p = Wg_[g] + hcol * ZSZ + ISZ + kf * 32 + 8 * lkg;
        bf16x8 f;
#pragma unroll
        for (int e = 0; e < 8; ++e) f[e] = (short)f2bf(p[e]);
        fragWh[g][kf] = f;
      }

    float cst[2], hh[2];
#pragma unroll
    for (int j = 0; j < 2; ++j)
      cst[j] = c0[(b0 + 2 * lkg + j) * HSZ + hcol];

    unsigned short* hout = (unsigned short*)out;  // bf16 h stash (head of probs rows)
    size_t stash = ((size_t)(b0 + 2 * lkg)) * (2 * VSZ) + hcol;

    int s3 = 0;
    for (int t = 0; t < T_STEPS; ++t) {
      // (1) x-part pre-activations from X-waves (usually ready)
      while (__hip_atomic_load(&xprod, __ATOMIC_ACQUIRE, WG_SCOPE) < 4 * (t + 1)) {}
      const float* gs = &gbuf[s3][0];
      f32x4 acc[4];
#pragma unroll
      for (int g = 0; g < 4; ++g)
        acc[g] = *(const f32x4*)&gs[(g * 64 + hcol) * GRD + 4 * lkg];

      // (2) wait for h[t]
      if (t)
        while (__hip_atomic_load(&pbar, __ATOMIC_ACQUIRE, WG_SCOPE) < 4 * t) {}

      const unsigned short* hrow = &hbuf[t & 1][lrow][0];
      const bf16x8 hf0 = *(const bf16x8*)&hrow[8 * lkg];
      const bf16x8 hf1 = *(const bf16x8*)&hrow[32 + 8 * lkg];
#pragma unroll
      for (int g = 0; g < 4; ++g)
        acc[g] = __builtin_amdgcn_mfma_f32_16x16x32_bf16(hf0, fragWh[g][0], acc[g], 0, 0, 0);
#pragma unroll
      for (int g = 0; g < 4; ++g)
        acc[g] = __builtin_amdgcn_mfma_f32_16x16x32_bf16(hf1, fragWh[g][1], acc[g], 0, 0, 0);

      // g slot consumed (values are in registers now)
      __builtin_amdgcn_sched_barrier(0);
      if (ln == 0) __hip_atomic_fetch_add(&pcons, 1, __ATOMIC_RELEASE, WG_SCOPE);

      // (3) redistribute: lane (lkg,lrow) takes rows 2lkg,2lkg+1 at col hcol
      const int src = (lkg >> 1) * 16 + lrow;
      const bool odd = (lkg & 1);
      float gv[4][2];
#pragma unroll
      for (int g = 0; g < 4; ++g) {
        float p0 = __shfl(acc[g][0], src);
        float p2 = __shfl(acc[g][2], src);
        float p1 = __shfl(acc[g][1], src);
        float p3 = __shfl(acc[g][3], src);
        gv[g][0] = odd ? p2 : p0;
        gv[g][1] = odd ? p3 : p1;
      }

      // (4) cell update: 2 valid cells per lane
#pragma unroll
      for (int j = 0; j < 2; ++j) {
        float fg = fsigmoid(gv[0][j]);
        float ig = fsigmoid(gv[1][j]);
        float cd = ftanh(gv[2][j]);
        float og = fsigmoid(gv[3][j]);
        float c  = cst[j] * fg + cd * ig;
        cst[j] = c;
        hh[j] = ftanh(c) * og;
      }

      // (5) publish h[t+1] to LDS ring + global stash for kernel B
      const int ns = (t + 1) & 1;
#pragma unroll
      for (int j = 0; j < 2; ++j) {
        const unsigned short hb = f2bf(hh[j]);
        hbuf[ns][2 * lkg + j][hcol] = hb;
        hout[stash + j * (2 * VSZ)] = hb;
      }
      __threadfence_block();
      if (ln == 0) __hip_atomic_fetch_add(&pbar, 1, __ATOMIC_RELEASE, WG_SCOPE);

      stash += (size_t)BATCH * (2 * VSZ);
      s3 = (s3 == 2) ? 0 : s3 + 1;
    }

    // final h/c outputs
#pragma unroll
    for (int j = 0; j < 2; ++j) {
      const int r = 2 * lkg + j;
      out[probs_elems + (size_t)(b0 + r) * HSZ + hcol] = hh[j];
      out[probs_elems + (size_t)BATCH * HSZ + (size_t)(b0 + r) * HSZ + hcol] = cst[j];
    }
  } else {
    // ================= X-wave: x[t]-GEMM producer, runs ahead =================
    const int xw = wv - 4;
    const int hcolX = 16 * xw + lrow;

    bf16x8 fragWx[4][4];
#pragma unroll
    for (int g = 0; g < 4; ++g)
#pragma unroll
      for (int kf = 0; kf < 4; ++kf) {
        const float* p = Wg_[g] + hcolX * ZSZ + kf * 32 + 8 * lkg;
        bf16x8 f;
#pragma unroll
        for (int e = 0; e < 8; ++e) f[e] = (short)f2bf(p[e]);
        fragWx[g][kf] = f;
      }
    float biasX[4];
#pragma unroll
    for (int g = 0; g < 4; ++g) biasX[g] = bg_[g][hcolX];

    const int rowx = min(b0 + lrow, BATCH - 1);
    const int xoff = 8 * lkg;

    // 2-step-deep raw pipeline (two named sets; all static indexing)
    f32x4 r0a[4], r0b[4], r1a[4], r1b[4];
    {
      const float* x0 = x + (size_t)rowx * ISZ;
      const float* x1 = x + (size_t)BATCH * ISZ + (size_t)rowx * ISZ;
#pragma unroll
      for (int kf = 0; kf < 4; ++kf) {
        r0a[kf] = *(const f32x4*)&x0[kf * 32 + xoff];
        r0b[kf] = *(const f32x4*)&x0[kf * 32 + xoff + 4];
        r1a[kf] = *(const f32x4*)&x1[kf * 32 + xoff];
        r1b[kf] = *(const f32x4*)&x1[kf * 32 + xoff + 4];
      }
    }

#define PRODUCE(U, SLOT, RA, RB)                                               \
    {                                                                          \
      bf16x8 xf[4];                                                            \
      _Pragma("unroll")                                                        \
      for (int kf = 0; kf < 4; ++kf) {                                         \
        bf16x8 f;                                                              \
        _Pragma("unroll")                                                      \
        for (int j = 0; j < 4; ++j) {                                          \
          f[j]     = (short)f2bf_hw(RA[kf][j]);                                \
          f[4 + j] = (short)f2bf_hw(RB[kf][j]);                                \
        }                                                                      \
        xf[kf] = f;                                                            \
      }                                                                        \
      if ((U) >= 3)                                                            \
        while (__hip_atomic_load(&pcons, __ATOMIC_ACQUIRE, WG_SCOPE) <         \
               4 * ((U) - 2)) {}                                               \
      f32x4 acc[4];                                                            \
      _Pragma("unroll")                                                        \
      for (int g = 0; g < 4; ++g)                                              \
        acc[g] = (f32x4){biasX[g], biasX[g], biasX[g], biasX[g]};              \
      _Pragma("unroll")                                                        \
      for (int kf = 0; kf < 4; ++kf)                                           \
        _Pragma("unroll")                                                      \
        for (int g = 0; g < 4; ++g)                                            \
          acc[g] = __builtin_amdgcn_mfma_f32_16x16x32_bf16(xf[kf],             \
                       fragWx[g][kf], acc[g], 0, 0, 0);                        \
      float* gsw = &gbuf[SLOT][0];                                             \
      _Pragma("unroll")                                                        \
      for (int g = 0; g < 4; ++g)                                              \
        *(f32x4*)&gsw[(g * 64 + hcolX) * GRD + 4 * lkg] = acc[g];              \
      __threadfence_block();                                                   \
      if (ln == 0) __hip_atomic_fetch_add(&xprod, 1, __ATOMIC_RELEASE, WG_SCOPE); \
      {                                                                        \
        const int tn = ((U) + 2 < T_STEPS) ? (U) + 2 : T_STEPS - 1;            \
        const float* xn = x + (size_t)tn * BATCH * ISZ + (size_t)rowx * ISZ;   \
        _Pragma("unroll")                                                      \
        for (int kf = 0; kf < 4; ++kf) {                                       \
          RA[kf] = *(const f32x4*)&xn[kf * 32 + xoff];                         \
          RB[kf] = *(const f32x4*)&xn[kf * 32 + xoff + 4];                     \
        }                                                                      \
      }                                                                        \
    }

    int slot = 0;
    for (int t = 0; t < T_STEPS; t += 2) {
      PRODUCE(t, slot, r0a, r0b);
      slot = (slot == 2) ? 0 : slot + 1;
      PRODUCE(t + 1, slot, r1a, r1b);
      slot = (slot == 2) ? 0 : slot + 1;
    }
#undef PRODUCE
  }
}

// ========== Kernel B: out-proj + softmax, fully parallel over T x B ==========
#define BBLOCKS 2048
__global__ __launch_bounds__(256) void lstm_out(
    const float* __restrict__ Wout, const float* __restrict__ bout_,
    float* __restrict__ out)
{
  const int tid  = threadIdx.x;
  const int wv   = tid >> 6;
  const int ln   = tid & 63;
  const int lrow = ln & 15;
  const int lkg  = ln >> 4;

  bf16x8 fragWo[8][2];
#pragma unroll
  for (int rf = 0; rf < 8; ++rf)
#pragma unroll
    for (int kf = 0; kf < 2; ++kf) {
      const float* p = Wout + (16 * rf + lrow) * HSZ + kf * 32 + 8 * lkg;
      bf16x8 f;
#pragma unroll
      for (int e = 0; e < 8; ++e) f[e] = (short)f2bf(p[e]);
      fragWo[rf][kf] = f;
    }
  f32x4 boV[8];
#pragma unroll
  for (int rf = 0; rf < 8; ++rf) boV[rf] = *(const f32x4*)&bout_[16 * rf + 4 * lkg];

  const unsigned short* hin = (const unsigned short*)out;
  const int NT = T_STEPS * (BATCH / 16);
  const int nw = BBLOCKS * 4;

  for (int tile = blockIdx.x * 4 + wv; tile < NT; tile += nw) {
    const int t  = tile >> 7;
    const int b0 = (tile & 127) * 16;

    const unsigned short* hr = hin + ((size_t)t * BATCH + b0 + lrow) * (2 * VSZ);
    const bf16x8 hb0 = *(const bf16x8*)&hr[8 * lkg];
    const bf16x8 hb1 = *(const bf16x8*)&hr[32 + 8 * lkg];

    f32x4 lac[8];
#pragma unroll
    for (int rf = 0; rf < 8; ++rf) {
      lac[rf] = boV[rf];
      lac[rf] = __builtin_amdgcn_mfma_f32_16x16x32_bf16(fragWo[rf][0], hb0, lac[rf], 0, 0, 0);
      lac[rf] = __builtin_amdgcn_mfma_f32_16x16x32_bf16(fragWo[rf][1], hb1, lac[rf], 0, 0, 0);
    }

    float m = -1e30f;
#pragma unroll
    for (int rf = 0; rf < 8; ++rf)
#pragma unroll
      for (int e = 0; e < 4; ++e) m = fmaxf(m, lac[rf][e]);
    m = fmaxf(m, __shfl_xor(m, 16));
    m = fmaxf(m, __shfl_xor(m, 32));
    float s = 0.0f;
#pragma unroll
    for (int rf = 0; rf < 8; ++rf)
#pragma unroll
      for (int e = 0; e < 4; ++e) {
        float p = __expf(lac[rf][e] - m);
        lac[rf][e] = p;
        s += p;
      }
    s += __shfl_xor(s, 16);
    s += __shfl_xor(s, 32);
    const float inv = 1.0f / s;

    float* orow = &out[((size_t)t * BATCH + b0 + lrow) * VSZ];
#pragma unroll
    for (int rf = 0; rf < 8; ++rf) {
      f32x4 pv = lac[rf] * inv;
      *(f32x4*)&orow[16 * rf + 4 * lkg] = pv;
    }
  }
}

extern "C" void kernel_launch(void* const* d_in, const int* in_sizes, int n_in,
                              void* d_out, int out_size, void* d_ws, size_t ws_size,
                              hipStream_t stream) {
  const float* x    = (const float*)d_in[0];
  const float* h0   = (const float*)d_in[1];
  const float* c0   = (const float*)d_in[2];
  const float* Wf   = (const float*)d_in[3];
  const float* bf_  = (const float*)d_in[4];
  const float* Wif  = (const float*)d_in[5];
  const float* bif_ = (const float*)d_in[6];
  const float* Wic  = (const float*)d_in[7];
  const float* bic_ = (const float*)d_in[8];
  const float* Wo   = (const float*)d_in[9];
  const float* bo_  = (const float*)d_in[10];
  const float* Wout = (const float*)d_in[11];
  const float* bout = (const float*)d_in[12];
  float* out = (float*)d_out;

  hipLaunchKernelGGL(lstm_rec, dim3(BATCH / MBLK), dim3(ATHREADS), 0, stream,
                     x, h0, c0, Wf, bf_, Wif, bif_, Wic, bic_, Wo, bo_, out);
  hipLaunchKernelGGL(lstm_out, dim3(BBLOCKS), dim3(256), 0, stream,
                     Wout, bout, out);
}

// Round 7
// 652.281 us; speedup vs baseline: 1.4892x; 1.3893x over previous
//
#include <hip/hip_runtime.h>
#include <hip/hip_bf16.h>

#define T_STEPS 512
#define BATCH   2048
#define ISZ     128
#define HSZ     64
#define VSZ     128
#define ZSZ     192   // I + H

#define MBLK    8     // batch rows per recurrence block -> 256 blocks
#define ATHREADS 512  // 4 P-waves + 4 X-waves
#define HLD     72    // hbuf row stride (bf16): 144 B
#define GRD     20    // gbuf row stride (floats): 16 rows + 4 pad, 16B-aligned frags
#define GSLOT   (4 * 64 * GRD)   // floats per ring slot

typedef __attribute__((ext_vector_type(8))) short bf16x8;
typedef __attribute__((ext_vector_type(4))) float f32x4;

__device__ __forceinline__ unsigned short f2bf(float x) {
  union { float f; unsigned int u; } v; v.f = x;
  unsigned int u = v.u;
  unsigned int r = (u + 0x7fffu + ((u >> 16) & 1u)) >> 16;  // RNE
  return (unsigned short)r;
}

__device__ __forceinline__ unsigned short f2bf_hw(float x) {
  __hip_bfloat16 b = __float2bfloat16(x);
  return *reinterpret_cast<unsigned short*>(&b);
}

__device__ __forceinline__ float fsigmoid(float x) {
  return 1.0f / (1.0f + __expf(-x));
}

__device__ __forceinline__ float ftanh(float x) {
  x = fminf(fmaxf(x, -15.0f), 15.0f);
  float e = __expf(-2.0f * x);
  return (1.0f - e) / (1.0f + e);
}

// ======== Kernel A: lockstep rounds — P (recurrence) + X (x-GEMM producer) ====
__global__ __launch_bounds__(ATHREADS, 1) void lstm_rec(
    const float* __restrict__ x,
    const float* __restrict__ h0,
    const float* __restrict__ c0,
    const float* __restrict__ Wf,  const float* __restrict__ bf_,
    const float* __restrict__ Wif, const float* __restrict__ bif_,
    const float* __restrict__ Wic, const float* __restrict__ bic_,
    const float* __restrict__ Wo,  const float* __restrict__ bo_,
    float* __restrict__ out)
{
  __shared__ float gbuf[3][GSLOT];            // x-part pre-activations, 3-ring
  __shared__ unsigned short hbuf[2][16][HLD]; // h state (bf16), 2-ring

  const int tid  = threadIdx.x;
  const int wv   = tid >> 6;     // 0..3 = P, 4..7 = X
  const int ln   = tid & 63;
  const int lrow = ln & 15;
  const int lkg  = ln >> 4;
  const int b0   = blockIdx.x * MBLK;

  // zero hbuf (rows 8..15 stay zero forever)
  for (int i = tid; i < 2 * 16 * HLD; i += ATHREADS)
    ((unsigned short*)hbuf)[i] = 0;
  __syncthreads();   // (A)
  if (tid < 256) {   // stage h0 rows 0..7 (done by P-wave threads)
    int idx = tid * 2, r = idx >> 6, c = idx & 63;
    hbuf[0][r][c]     = f2bf(h0[(b0 + r) * HSZ + c]);
    hbuf[0][r][c + 1] = f2bf(h0[(b0 + r) * HSZ + c + 1]);
  }

  const float* Wg_[4] = {Wf, Wif, Wic, Wo};
  const float* bg_[4] = {bf_, bif_, bic_, bo_};
  const size_t probs_elems = (size_t)T_STEPS * BATCH * VSZ;

  if (wv < 4) {
    // ================= P-wave: minimal serial chain =================
    const int hcol = 16 * wv + lrow;

    bf16x8 fragWh[4][2];
#pragma unroll
    for (int g = 0; g < 4; ++g)
#pragma unroll
      for (int kf = 0; kf < 2; ++kf) {
        const float* p = Wg_[g] + hcol * ZSZ + ISZ + kf * 32 + 8 * lkg;
        bf16x8 f;
#pragma unroll
        for (int e = 0; e < 8; ++e) f[e] = (short)f2bf(p[e]);
        fragWh[g][kf] = f;
      }

    float cst[2], hh[2];
#pragma unroll
    for (int j = 0; j < 2; ++j)
      cst[j] = c0[(b0 + 2 * lkg + j) * HSZ + hcol];

    unsigned short* hstash = (unsigned short*)out +
                             ((size_t)(b0 + 2 * lkg)) * (2 * VSZ) + hcol;

    __syncthreads();   // (B): X produced g[0], g[1]

    // preload acc for round 0 (g[0], slot 0)
    f32x4 acc[4];
#pragma unroll
    for (int g = 0; g < 4; ++g)
      acc[g] = *(const f32x4*)&gbuf[0][(g * 64 + hcol) * GRD + 4 * lkg];

    int sA = 0;   // slot of the PRELOADED acc (for step t)
    int ht = 0;   // hbuf slot holding h[t]
    for (int t = 0; t < T_STEPS; ++t) {
      __builtin_amdgcn_s_barrier();
      asm volatile("" ::: "memory");

      // h[t] fragments + 8 MFMAs on top of preloaded x-part acc
      const unsigned short* hrow = &hbuf[ht][lrow][0];
      const bf16x8 hf0 = *(const bf16x8*)&hrow[8 * lkg];
      const bf16x8 hf1 = *(const bf16x8*)&hrow[32 + 8 * lkg];
      f32x4 cur[4];
#pragma unroll
      for (int g = 0; g < 4; ++g)
        cur[g] = __builtin_amdgcn_mfma_f32_16x16x32_bf16(hf0, fragWh[g][0], acc[g], 0, 0, 0);
#pragma unroll
      for (int g = 0; g < 4; ++g)
        cur[g] = __builtin_amdgcn_mfma_f32_16x16x32_bf16(hf1, fragWh[g][1], cur[g], 0, 0, 0);

      // preload next round's x-part acc (g[t+1] ready since barrier t; off-chain)
      sA = (sA == 2) ? 0 : sA + 1;
      {
        const float* gs = &gbuf[sA][0];
#pragma unroll
        for (int g = 0; g < 4; ++g)
          acc[g] = *(const f32x4*)&gs[(g * 64 + hcol) * GRD + 4 * lkg];
      }

      // redistribute: lane (lkg,lrow) takes rows 2lkg,2lkg+1 at col hcol
      const int src = (lkg >> 1) * 16 + lrow;
      const bool odd = (lkg & 1);
      float gv[4][2];
#pragma unroll
      for (int g = 0; g < 4; ++g) {
        float p0 = __shfl(cur[g][0], src);
        float p2 = __shfl(cur[g][2], src);
        float p1 = __shfl(cur[g][1], src);
        float p3 = __shfl(cur[g][3], src);
        gv[g][0] = odd ? p2 : p0;
        gv[g][1] = odd ? p3 : p1;
      }

      // cell update: 2 valid cells per lane
#pragma unroll
      for (int j = 0; j < 2; ++j) {
        float fg = fsigmoid(gv[0][j]);
        float ig = fsigmoid(gv[1][j]);
        float cd = ftanh(gv[2][j]);
        float og = fsigmoid(gv[3][j]);
        float c  = cst[j] * fg + cd * ig;
        cst[j] = c;
        hh[j] = ftanh(c) * og;
      }

      // publish h[t+1] (LDS ring + global stash; stash is never waited on)
      ht ^= 1;
      const unsigned short hb0w = f2bf_hw(hh[0]);
      const unsigned short hb1w = f2bf_hw(hh[1]);
      hbuf[ht][2 * lkg][hcol]     = hb0w;
      hbuf[ht][2 * lkg + 1][hcol] = hb1w;
      hstash[0]       = hb0w;
      hstash[2 * VSZ] = hb1w;
      hstash += (size_t)BATCH * (2 * VSZ);

      asm volatile("s_waitcnt lgkmcnt(0)" ::: "memory");  // flush LDS writes (+preload reads)
    }

    // final h/c outputs
#pragma unroll
    for (int j = 0; j < 2; ++j) {
      const int r = 2 * lkg + j;
      out[probs_elems + (size_t)(b0 + r) * HSZ + hcol] = hh[j];
      out[probs_elems + (size_t)BATCH * HSZ + (size_t)(b0 + r) * HSZ + hcol] = cst[j];
    }
  } else {
    // ================= X-wave: x[t]-GEMM producer, 2 rounds ahead ============
    const int xw = wv - 4;
    const int hcolX = 16 * xw + lrow;

    bf16x8 fragWx[4][4];
#pragma unroll
    for (int g = 0; g < 4; ++g)
#pragma unroll
      for (int kf = 0; kf < 4; ++kf) {
        const float* p = Wg_[g] + hcolX * ZSZ + kf * 32 + 8 * lkg;
        bf16x8 f;
#pragma unroll
        for (int e = 0; e < 8; ++e) f[e] = (short)f2bf(p[e]);
        fragWx[g][kf] = f;
      }
    float biasX[4];
#pragma unroll
    for (int g = 0; g < 4; ++g) biasX[g] = bg_[g][hcolX];

    const int rowx = min(b0 + lrow, BATCH - 1);
    const int xoff = 8 * lkg;

    f32x4 rEa[4], rEb[4], rOa[4], rOb[4];

#define XLOAD(TT, RA, RB)                                                      \
    {                                                                          \
      const int tc = ((TT) < T_STEPS) ? (TT) : T_STEPS - 1;                    \
      const float* xp = x + (size_t)tc * BATCH * ISZ + (size_t)rowx * ISZ;     \
      _Pragma("unroll")                                                        \
      for (int kf = 0; kf < 4; ++kf) {                                         \
        RA[kf] = *(const f32x4*)&xp[kf * 32 + xoff];                           \
        RB[kf] = *(const f32x4*)&xp[kf * 32 + xoff + 4];                       \
      }                                                                        \
    }

#define XPRODUCE(U, SLOT, RA, RB)                                              \
    if ((U) < T_STEPS) {                                                       \
      bf16x8 xf[4];                                                            \
      _Pragma("unroll")                                                        \
      for (int kf = 0; kf < 4; ++kf) {                                         \
        bf16x8 f;                                                              \
        _Pragma("unroll")                                                      \
        for (int j = 0; j < 4; ++j) {                                          \
          f[j]     = (short)f2bf_hw(RA[kf][j]);                                \
          f[4 + j] = (short)f2bf_hw(RB[kf][j]);                                \
        }                                                                      \
        xf[kf] = f;                                                            \
      }                                                                        \
      f32x4 xacc[4];                                                           \
      _Pragma("unroll")                                                        \
      for (int g = 0; g < 4; ++g)                                              \
        xacc[g] = (f32x4){biasX[g], biasX[g], biasX[g], biasX[g]};             \
      _Pragma("unroll")                                                        \
      for (int kf = 0; kf < 4; ++kf)                                           \
        _Pragma("unroll")                                                      \
        for (int g = 0; g < 4; ++g)                                            \
          xacc[g] = __builtin_amdgcn_mfma_f32_16x16x32_bf16(                   \
              xf[kf], fragWx[g][kf], xacc[g], 0, 0, 0);                        \
      float* gsw = &gbuf[SLOT][0];                                             \
      _Pragma("unroll")                                                        \
      for (int g = 0; g < 4; ++g)                                              \
        *(f32x4*)&gsw[(g * 64 + hcolX) * GRD + 4 * lkg] = xacc[g];             \
    }

    // prologue: produce g[0], g[1]; leave x[2],x[3] in flight
    XLOAD(0, rEa, rEb);
    XLOAD(1, rOa, rOb);
    XPRODUCE(0, 0, rEa, rEb);
    XPRODUCE(1, 1, rOa, rOb);
    XLOAD(2, rEa, rEb);
    XLOAD(3, rOa, rOb);
    asm volatile("s_waitcnt lgkmcnt(0)" ::: "memory");
    __syncthreads();   // (B)

    int se = 2;  // slot for even-parity produce (g[t+2] at even t)
    int so = 0;  // slot for odd-parity produce  (g[t+3])
    for (int t = 0; t < T_STEPS; t += 2) {
      __builtin_amdgcn_s_barrier();
      asm volatile("" ::: "memory");
      XPRODUCE(t + 2, se, rEa, rEb);
      XLOAD(t + 4, rEa, rEb);
      se += 2; if (se >= 3) se -= 3;
      asm volatile("s_waitcnt lgkmcnt(0)" ::: "memory");

      __builtin_amdgcn_s_barrier();
      asm volatile("" ::: "memory");
      XPRODUCE(t + 3, so, rOa, rOb);
      XLOAD(t + 5, rOa, rOb);
      so += 2; if (so >= 3) so -= 3;
      asm volatile("s_waitcnt lgkmcnt(0)" ::: "memory");
    }
#undef XPRODUCE
#undef XLOAD
  }
}

// ========== Kernel B: out-proj + softmax, fully parallel over T x B ==========
#define BBLOCKS 2048
__global__ __launch_bounds__(256) void lstm_out(
    const float* __restrict__ Wout, const float* __restrict__ bout_,
    float* __restrict__ out)
{
  const int tid  = threadIdx.x;
  const int wv   = tid >> 6;
  const int ln   = tid & 63;
  const int lrow = ln & 15;
  const int lkg  = ln >> 4;

  bf16x8 fragWo[8][2];
#pragma unroll
  for (int rf = 0; rf < 8; ++rf)
#pragma unroll
    for (int kf = 0; kf < 2; ++kf) {
      const float* p = Wout + (16 * rf + lrow) * HSZ + kf * 32 + 8 * lkg;
      bf16x8 f;
#pragma unroll
      for (int e = 0; e < 8; ++e) f[e] = (short)f2bf(p[e]);
      fragWo[rf][kf] = f;
    }
  f32x4 boV[8];
#pragma unroll
  for (int rf = 0; rf < 8; ++rf) boV[rf] = *(const f32x4*)&bout_[16 * rf + 4 * lkg];

  const unsigned short* hin = (const unsigned short*)out;
  const int NT = T_STEPS * (BATCH / 16);
  const int nw = BBLOCKS * 4;

  for (int tile = blockIdx.x * 4 + wv; tile < NT; tile += nw) {
    const int t  = tile >> 7;
    const int b0 = (tile & 127) * 16;

    const unsigned short* hr = hin + ((size_t)t * BATCH + b0 + lrow) * (2 * VSZ);
    const bf16x8 hb0 = *(const bf16x8*)&hr[8 * lkg];
    const bf16x8 hb1 = *(const bf16x8*)&hr[32 + 8 * lkg];

    f32x4 lac[8];
#pragma unroll
    for (int rf = 0; rf < 8; ++rf) {
      lac[rf] = boV[rf];
      lac[rf] = __builtin_amdgcn_mfma_f32_16x16x32_bf16(fragWo[rf][0], hb0, lac[rf], 0, 0, 0);
      lac[rf] = __builtin_amdgcn_mfma_f32_16x16x32_bf16(fragWo[rf][1], hb1, lac[rf], 0, 0, 0);
    }

    float m = -1e30f;
#pragma unroll
    for (int rf = 0; rf < 8; ++rf)
#pragma unroll
      for (int e = 0; e < 4; ++e) m = fmaxf(m, lac[rf][e]);
    m = fmaxf(m, __shfl_xor(m, 16));
    m = fmaxf(m, __shfl_xor(m, 32));
    float s = 0.0f;
#pragma unroll
    for (int rf = 0; rf < 8; ++rf)
#pragma unroll
      for (int e = 0; e < 4; ++e) {
        float p = __expf(lac[rf][e] - m);
        lac[rf][e] = p;
        s += p;
      }
    s += __shfl_xor(s, 16);
    s += __shfl_xor(s, 32);
    const float inv = 1.0f / s;

    float* orow = &out[((size_t)t * BATCH + b0 + lrow) * VSZ];
#pragma unroll
    for (int rf = 0; rf < 8; ++rf) {
      f32x4 pv = lac[rf] * inv;
      *(f32x4*)&orow[16 * rf + 4 * lkg] = pv;
    }
  }
}

extern "C" void kernel_launch(void* const* d_in, const int* in_sizes, int n_in,
                              void* d_out, int out_size, void* d_ws, size_t ws_size,
                              hipStream_t stream) {
  const float* x    = (const float*)d_in[0];
  const float* h0   = (const float*)d_in[1];
  const float* c0   = (const float*)d_in[2];
  const float* Wf   = (const float*)d_in[3];
  const float* bf_  = (const float*)d_in[4];
  const float* Wif  = (const float*)d_in[5];
  const float* bif_ = (const float*)d_in[6];
  const float* Wic  = (const float*)d_in[7];
  const float* bic_ = (const float*)d_in[8];
  const float* Wo   = (const float*)d_in[9];
  const float* bo_  = (const float*)d_in[10];
  const float* Wout = (const float*)d_in[11];
  const float* bout = (const float*)d_in[12];
  float* out = (float*)d_out;

  hipLaunchKernelGGL(lstm_rec, dim3(BATCH / MBLK), dim3(ATHREADS), 0, stream,
                     x, h0, c0, Wf, bf_, Wif, bif_, Wic, bic_, Wo, bo_, out);
  hipLaunchKernelGGL(lstm_out, dim3(BBLOCKS), dim3(256), 0, stream,
                     Wout, bout, out);
}